// Round 14
// baseline (418.334 us; speedup 1.0000x reference)
//
#include <hip/hip_runtime.h>
#include <hip/hip_bf16.h>

#define EPSQ 1e-7f

#define BSZ 128
#define M2 4608           // B*36 conv2 output positions
#define K2 20736          // 81*256
#define KSTEPS 648        // K2/32

// ws offsets in floats (liveness-overlapped).
// c1p: packed hi/lo conv1 output, 51200 pos x 512 ushorts = 13,107,200 fl region.
// w2tp: packed hi/lo w2^T, 256 n x 41472 ushorts = 5,308,416 fl region.
#define WS_C1P   0              // [0, 13,107,200) fl
#define WS_W2TP  13107200       // [13,107,200, 18,415,616) fl
#define WS_CPART 18415616
#define WS_PC    0              // 1,179,648 fl (c1p dead after conv2)
#define WS_S12A  1179648        // 40,960 fl: s1acc [0,20480) + s2acc [20480,40960)
#define WS_H1    13107200       // 65,536 (w2tp dead)
#define WS_H2    13172736       // 131,072

typedef __attribute__((ext_vector_type(8))) short short8;
typedef __attribute__((ext_vector_type(4))) float floatx4;

#define DOT8(W0, W1, P) ((W0).x*(P)[0] + (W0).y*(P)[1] + (W0).z*(P)[2] + (W0).w*(P)[3] + \
                         (W1).x*(P)[4] + (W1).y*(P)[5] + (W1).z*(P)[6] + (W1).w*(P)[7])

__device__ inline ushort bf16_rne(float x) {
    union { float f; unsigned u; } v; v.f = x;
    unsigned r = v.u + 0x7FFFu + ((v.u >> 16) & 1u);
    return (ushort)(r >> 16);
}
__device__ inline float bf16_to_f(ushort h) {
    union { unsigned u; float f; } v; v.u = ((unsigned)h) << 16;
    return v.f;
}

// ---------------- fused conv1 (blocks [0,2560)) + w2 transpose ([2560,3856)) ----
// Outputs PACKED hi/lo: unit of 8 ic -> 16B hi then 16B lo (32B), so conv2 reads
// 256B contiguous bursts per (position, 64-ic chunk).
__global__ __launch_bounds__(256) void convprep_kernel(const float* __restrict__ img,
        const float* __restrict__ w1, const float* __restrict__ b1,
        const float* __restrict__ w2,
        ushort* __restrict__ c1p, ushort* __restrict__ w2tp) {
    __shared__ float sm[4160];
    int t = threadIdx.x;
    int bid = blockIdx.x;
    if (bid < 2560) {
        int b = bid / 20, oh = bid % 20;
        if (t < 252) sm[t] = img[b * 784 + oh * 28 + t];
        __syncthreads();
        float acc[20];
#pragma unroll
        for (int ow = 0; ow < 20; ++ow) acc[ow] = 0.f;
        for (int kh = 0; kh < 9; ++kh) {
            float row[28];
#pragma unroll
            for (int c = 0; c < 28; ++c) row[c] = sm[kh * 28 + c];
#pragma unroll
            for (int kw = 0; kw < 9; ++kw) {
                float wv = w1[(kh * 9 + kw) * 256 + t];
#pragma unroll
                for (int ow = 0; ow < 20; ++ow) acc[ow] += row[kw + ow] * wv;
            }
        }
        float bias = b1[t];
        // packed addr: pos*512 + (ic>>3)*16 + (ic&7); lo at +8
        size_t pbase = ((size_t)(b * 20 + oh) * 20) * 512 + (t >> 3) * 16 + (t & 7);
#pragma unroll
        for (int ow = 0; ow < 20; ++ow) {
            float x = fmaxf(acc[ow] + bias, 0.f);
            ushort h = bf16_rne(x);
            size_t a = pbase + (size_t)ow * 512;
            c1p[a] = h;
            c1p[a + 8] = bf16_rne(x - bf16_to_f(h));
        }
    } else {
        int pb = bid - 2560;                 // 1296 = 324 kt x 4 nt
        int kt = pb >> 2, nt = pb & 3;
        int tn = t & 63, t4 = t >> 6;
#pragma unroll
        for (int i = 0; i < 16; ++i) {
            int k = i * 4 + t4;
            sm[k * 65 + tn] = w2[(size_t)(kt * 64 + k) * 256 + nt * 64 + tn];
        }
        __syncthreads();
        int tk = t & 63;
#pragma unroll
        for (int i = 0; i < 16; ++i) {
            int n = i * 4 + t4;
            float x = sm[tk * 65 + n];
            ushort h = bf16_rne(x);
            ushort lo = bf16_rne(x - bf16_to_f(h));
            int kg = kt * 64 + tk;
            size_t o = (size_t)(nt * 64 + n) * 41472 + (size_t)(kg >> 3) * 16 + (kg & 7);
            w2tp[o] = h; w2tp[o + 8] = lo;
        }
    }
}

// -------- conv2 MFMA GEMM (R6-verified core; packed 256B-burst global reads) ----
#define LDS_AH 0
#define LDS_AL 4096
#define LDS_BH 8192
#define LDS_BL 16384
__global__ __launch_bounds__(256) void conv2_mfma_kernel(
        const ushort* __restrict__ c1p, const ushort* __restrict__ w2tp,
        float* __restrict__ part, int nsteps, int nwg) {
    int bid = blockIdx.x;
    int v = (bid & 7) * (nwg >> 3) + (bid >> 3);   // bijective: 8 | nwg
    int mt = v % 72, grp = v / 72;
    int nt = grp & 1, ks = grp >> 1;
    int t = threadIdx.x;
    int m0 = mt * 64, n0 = nt * 128;
    __shared__ __attribute__((aligned(16))) ushort lds[24576];   // 48 KB

    int sr = t >> 3, sc = t & 7;
    int mA0 = m0 + sr, mA1 = m0 + sr + 32;
    int b0_ = mA0 / 36, r0_ = mA0 % 36;
    int b1_ = mA1 / 36, r1_ = mA1 % 36;
    int pp0 = (b0_ * 20 + (r0_ / 6) * 2) * 20 + (r0_ % 6) * 2;   // position index
    int pp1 = (b1_ * 20 + (r1_ / 6) * 2) * 20 + (r1_ % 6) * 2;
    size_t wbB = (size_t)(n0 + sr) * 41472 + sc * 16;
    int wOff = sr * 64 + ((sc ^ (sr & 7)) * 8);

    int lane = t & 63, wave = t >> 6;
    int l15 = lane & 15, g = lane >> 4;
    int wrb = (wave >> 1) * 32, wcb = (wave & 1) * 64;

    floatx4 acc[2][4];
#pragma unroll
    for (int mi = 0; mi < 2; ++mi)
#pragma unroll
        for (int nj = 0; nj < 4; ++nj) acc[mi][nj] = (floatx4)0.f;

    int st0 = ks * nsteps;
    uint4 A0h, A1h, A0l, A1l, B0h, B1h, B2h, B3h, B0l, B1l, B2l, B3l;
#define LOADG64(ST) { \
        int kb = (ST) * 64; \
        int khkw = kb >> 8; int kh = khkw / 9, kw = khkw - kh * 9; \
        int ic2 = (((kb & 255) + sc * 8) << 1); \
        size_t a0 = (size_t)(pp0 + kh * 20 + kw) * 512 + ic2; \
        size_t a1 = (size_t)(pp1 + kh * 20 + kw) * 512 + ic2; \
        A0h = *(const uint4*)(c1p + a0); \
        A0l = *(const uint4*)(c1p + a0 + 8); \
        A1h = *(const uint4*)(c1p + a1); \
        A1l = *(const uint4*)(c1p + a1 + 8); \
        size_t bo = wbB + (size_t)kb * 2; \
        B0h = *(const uint4*)(w2tp + bo); \
        B0l = *(const uint4*)(w2tp + bo + 8); \
        B1h = *(const uint4*)(w2tp + bo + (size_t)32 * 41472); \
        B1l = *(const uint4*)(w2tp + bo + (size_t)32 * 41472 + 8); \
        B2h = *(const uint4*)(w2tp + bo + (size_t)64 * 41472); \
        B2l = *(const uint4*)(w2tp + bo + (size_t)64 * 41472 + 8); \
        B3h = *(const uint4*)(w2tp + bo + (size_t)96 * 41472); \
        B3l = *(const uint4*)(w2tp + bo + (size_t)96 * 41472 + 8); }

    LOADG64(st0);
    for (int st = 0; st < nsteps; ++st) {
        __syncthreads();
        *(uint4*)&lds[LDS_AH + wOff]        = A0h;
        *(uint4*)&lds[LDS_AH + wOff + 2048] = A1h;
        *(uint4*)&lds[LDS_AL + wOff]        = A0l;
        *(uint4*)&lds[LDS_AL + wOff + 2048] = A1l;
        *(uint4*)&lds[LDS_BH + wOff]        = B0h;
        *(uint4*)&lds[LDS_BH + wOff + 2048] = B1h;
        *(uint4*)&lds[LDS_BH + wOff + 4096] = B2h;
        *(uint4*)&lds[LDS_BH + wOff + 6144] = B3h;
        *(uint4*)&lds[LDS_BL + wOff]        = B0l;
        *(uint4*)&lds[LDS_BL + wOff + 2048] = B1l;
        *(uint4*)&lds[LDS_BL + wOff + 4096] = B2l;
        *(uint4*)&lds[LDS_BL + wOff + 6144] = B3l;
        __syncthreads();
        if (st + 1 < nsteps) LOADG64(st0 + st + 1);

#pragma unroll
        for (int kk = 0; kk < 2; ++kk) {
            int sl = kk * 4 + g;
            short8 ah[2], al[2], bh[4], bl[4];
#pragma unroll
            for (int mi = 0; mi < 2; ++mi) {
                int r = wrb + mi * 16 + l15;
                int ro = r * 64 + ((sl ^ (r & 7)) * 8);
                ah[mi] = *(const short8*)&lds[LDS_AH + ro];
                al[mi] = *(const short8*)&lds[LDS_AL + ro];
            }
#pragma unroll
            for (int nj = 0; nj < 4; ++nj) {
                int c = wcb + nj * 16 + l15;
                int co = c * 64 + ((sl ^ (c & 7)) * 8);
                bh[nj] = *(const short8*)&lds[LDS_BH + co];
                bl[nj] = *(const short8*)&lds[LDS_BL + co];
            }
#pragma unroll
            for (int mi = 0; mi < 2; ++mi)
#pragma unroll
                for (int nj = 0; nj < 4; ++nj) {
                    acc[mi][nj] = __builtin_amdgcn_mfma_f32_16x16x32_bf16(ah[mi], bh[nj], acc[mi][nj], 0, 0, 0);
                    acc[mi][nj] = __builtin_amdgcn_mfma_f32_16x16x32_bf16(ah[mi], bl[nj], acc[mi][nj], 0, 0, 0);
                    acc[mi][nj] = __builtin_amdgcn_mfma_f32_16x16x32_bf16(al[mi], bh[nj], acc[mi][nj], 0, 0, 0);
                }
        }
    }
    __syncthreads();
    float* ldsf = (float*)lds;
#pragma unroll
    for (int mi = 0; mi < 2; ++mi)
#pragma unroll
        for (int nj = 0; nj < 4; ++nj) {
            int col = wcb + nj * 16 + l15;
            int rw = wrb + mi * 16 + (lane >> 4) * 4;
#pragma unroll
            for (int r = 0; r < 4; ++r)
                ldsf[(rw + r) * 132 + col] = acc[mi][nj][r];
        }
    __syncthreads();
    size_t obase = (size_t)ks * M2 * 256;
#pragma unroll
    for (int i = 0; i < 8; ++i) {
        int f = i * 256 + t;          // float4 id 0..2047
        int row = f >> 5, c4 = f & 31;
        float4 val = *(const float4*)&ldsf[row * 132 + c4 * 4];
        *(float4*)&part[obase + (size_t)(m0 + row) * 256 + n0 + c4 * 4] = val;
    }
}

// -------- reduce k-split partials + bias + relu + squash(8) -> pc; zero s12acc --
__global__ __launch_bounds__(256) void squash_pc_kernel(const float* __restrict__ part,
        const float* __restrict__ b2, float* __restrict__ pc,
        float* __restrict__ s12acc, int nsplit) {
    int m = blockIdx.x;
    int n = threadIdx.x;
    if (m < 160) s12acc[m * 256 + n] = 0.f;   // zero s1acc+s2acc (40960 fl)
    size_t idx = (size_t)m * 256 + n;
    const size_t stride = (size_t)M2 * 256;
    float v = 0.f;
    for (int s = 0; s < nsplit; ++s) v += part[idx + s * stride];
    v = fmaxf(v + b2[n], 0.f);
    float sq = v * v;
    sq += __shfl_xor(sq, 1, 8);
    sq += __shfl_xor(sq, 2, 8);
    sq += __shfl_xor(sq, 4, 8);
    float scale = sq / ((1.f + sq) * sqrtf(sq + EPSQ));
    pc[idx] = v * scale;
}

// -------- s1: grid (144 x 8), W in regs, atomic accumulation into s1acc ---------
__global__ __launch_bounds__(192) void s1part_kernel(const float* __restrict__ Wm,
        const float* __restrict__ pc, float* __restrict__ s1acc) {
    int ic = blockIdx.x, bg = blockIdx.y;
    int i0 = ic * 8, b0 = bg * 16;
    int t = threadIdx.x;
    __shared__ float pcl[16][68];
    for (int e = t; e < 1024; e += 192) {
        int bl = e >> 6, off = e & 63;
        pcl[bl][off] = pc[(size_t)(b0 + bl) * 9216 + i0 * 8 + off];
    }
    __syncthreads();
    if (t >= 160) return;
    float4 w[8][2];
#pragma unroll
    for (int ii = 0; ii < 8; ++ii) {
        const float4* wp = (const float4*)&Wm[(size_t)(i0 + ii) * 1280 + t * 8];
        w[ii][0] = wp[0]; w[ii][1] = wp[1];
    }
    for (int bl = 0; bl < 16; ++bl) {
        float s = 0.f;
#pragma unroll
        for (int ii = 0; ii < 8; ++ii) {
            const float* p = &pcl[bl][ii * 8];
            s += DOT8(w[ii][0], w[ii][1], p);
        }
        atomicAdd(&s1acc[(b0 + bl) * 160 + t], s);
    }
}

// -------- c2s2: v1 squash folded in; agreement+softmax; atomic s2 accumulation --
__global__ __launch_bounds__(192) void c2s2_kernel(const float* __restrict__ Wm,
        const float* __restrict__ pc, const float* __restrict__ s1acc,
        float* __restrict__ s2acc) {
    int ic = blockIdx.x, bg = blockIdx.y;
    int i0 = ic * 8, b0 = bg * 16;
    int t = threadIdx.x;
    __shared__ float pcl[16][68];
    __shared__ float uvl[8][16][10];
    for (int e = t; e < 1024; e += 192) {
        int bl = e >> 6, off = e & 63;
        pcl[bl][off] = pc[(size_t)(b0 + bl) * 9216 + i0 * 8 + off];
    }
    __syncthreads();
    int j = t >> 4;
    float4 w[8][2];
    if (t < 160) {
#pragma unroll
        for (int ii = 0; ii < 8; ++ii) {
            const float4* wp = (const float4*)&Wm[(size_t)(i0 + ii) * 1280 + t * 8];
            w[ii][0] = wp[0]; w[ii][1] = wp[1];
        }
        for (int bl = 0; bl < 16; ++bl) {
            float s1v = s1acc[(b0 + bl) * 160 + t] * 0.1f;
            float q = s1v * s1v;
            q += __shfl_xor(q, 1, 16);
            q += __shfl_xor(q, 2, 16);
            q += __shfl_xor(q, 4, 16);
            q += __shfl_xor(q, 8, 16);
            float vv = s1v * q / ((1.f + q) * sqrtf(q + EPSQ));
#pragma unroll
            for (int ii = 0; ii < 8; ++ii) {
                const float* p = &pcl[bl][ii * 8];
                float u = DOT8(w[ii][0], w[ii][1], p);
                float pr = u * vv;
                pr += __shfl_xor(pr, 1, 16);
                pr += __shfl_xor(pr, 2, 16);
                pr += __shfl_xor(pr, 4, 16);
                pr += __shfl_xor(pr, 8, 16);
                if ((t & 15) == 0) uvl[ii][bl][j] = pr;
            }
        }
    }
    __syncthreads();
    if (t < 128) {
        int ii = t >> 4, bl = t & 15;
        float* uv = uvl[ii][bl];
        float mx = uv[0];
#pragma unroll
        for (int jj = 1; jj < 10; ++jj) mx = fmaxf(mx, uv[jj]);
        float sum = 0.f;
        float ex[10];
#pragma unroll
        for (int jj = 0; jj < 10; ++jj) { ex[jj] = expf(uv[jj] - mx); sum += ex[jj]; }
        float inv = 1.f / sum;
#pragma unroll
        for (int jj = 0; jj < 10; ++jj) uv[jj] = ex[jj] * inv;
    }
    __syncthreads();
    if (t >= 160) return;
    for (int bl = 0; bl < 16; ++bl) {
        float acc = 0.f;
#pragma unroll
        for (int ii = 0; ii < 8; ++ii) {
            const float* p = &pcl[bl][ii * 8];
            float u = DOT8(w[ii][0], w[ii][1], p);
            acc += uvl[ii][bl][j] * u;
        }
        atomicAdd(&s2acc[(b0 + bl) * 160 + t], acc);
    }
}

// ======== batch-grouped decoder: weights read 32x instead of 128x ===============
#define DGRP 4

// -------- fc1: fused v2-squash/norm/argmax/mask preamble + GEMM -----------------
__global__ __launch_bounds__(256) void fc1_kernel(const float* __restrict__ s2acc,
        const int* __restrict__ target, const float* __restrict__ w,
        const float* __restrict__ bias, float* __restrict__ out,
        float* __restrict__ h1) {
    int nc = blockIdx.x;                 // 0..1
    int b0 = blockIdx.y * DGRP;
    int t = threadIdx.x;
    __shared__ float sk[DGRP][160];
    __shared__ float nl[DGRP][10];
    for (int bb = 0; bb < DGRP; ++bb) {
        if (t < 160) {
            int b = b0 + bb;
            float s = s2acc[b * 160 + t];
            float sq = s * s;
            sq += __shfl_xor(sq, 1, 16);
            sq += __shfl_xor(sq, 2, 16);
            sq += __shfl_xor(sq, 4, 16);
            sq += __shfl_xor(sq, 8, 16);
            float v = s * sq / ((1.f + sq) * sqrtf(sq + EPSQ));
            float vsq = v * v;
            vsq += __shfl_xor(vsq, 1, 16);
            vsq += __shfl_xor(vsq, 2, 16);
            vsq += __shfl_xor(vsq, 4, 16);
            vsq += __shfl_xor(vsq, 8, 16);
            float norm = sqrtf(vsq + EPSQ);
            int j = t >> 4;
            sk[bb][t] = (j == target[b]) ? v : 0.f;
            if ((t & 15) == 0) {
                nl[bb][j] = norm;
                if (nc == 0) out[b * 10 + j] = norm;
            }
        }
    }
    __syncthreads();
    if (nc == 0 && t < DGRP) {
        float best = nl[t][0]; int am = 0;
#pragma unroll
        for (int jj = 1; jj < 10; ++jj) if (nl[t][jj] > best) { best = nl[t][jj]; am = jj; }
        out[1280 + b0 + t] = (float)am;
    }
    int n = nc * 256 + t;
    float acc[DGRP];
#pragma unroll
    for (int bb = 0; bb < DGRP; ++bb) acc[bb] = bias[n];
    for (int k = 0; k < 160; ++k) {
        float wv = w[k * 512 + n];
#pragma unroll
        for (int bb = 0; bb < DGRP; ++bb) acc[bb] += sk[bb][k] * wv;
    }
#pragma unroll
    for (int bb = 0; bb < DGRP; ++bb)
        h1[(size_t)(b0 + bb) * 512 + n] = fmaxf(acc[bb], 0.f);
}

// -------- fc2: relu, batch-grouped ----------------------------------------------
__global__ __launch_bounds__(256) void fc2_kernel(const float* __restrict__ h1,
        const float* __restrict__ w, const float* __restrict__ bias,
        float* __restrict__ h2) {
    int nc = blockIdx.x;                 // 0..3
    int b0 = blockIdx.y * DGRP;
    int t = threadIdx.x;
    __shared__ float sk[DGRP][512];
    for (int e = t; e < DGRP * 512; e += 256) {
        int bb = e >> 9, k = e & 511;
        sk[bb][k] = h1[(size_t)(b0 + bb) * 512 + k];
    }
    __syncthreads();
    int n = nc * 256 + t;
    float acc[DGRP];
#pragma unroll
    for (int bb = 0; bb < DGRP; ++bb) acc[bb] = bias[n];
    for (int k = 0; k < 512; ++k) {
        float wv = w[(size_t)k * 1024 + n];
#pragma unroll
        for (int bb = 0; bb < DGRP; ++bb) acc[bb] += sk[bb][k] * wv;
    }
#pragma unroll
    for (int bb = 0; bb < DGRP; ++bb)
        h2[(size_t)(b0 + bb) * 1024 + n] = fmaxf(acc[bb], 0.f);
}

// -------- fc3: sigmoid, batch-grouped -------------------------------------------
__global__ __launch_bounds__(256) void fc3_kernel(const float* __restrict__ h2,
        const float* __restrict__ w, const float* __restrict__ bias,
        float* __restrict__ out) {
    int nc = blockIdx.x;                 // 0..3, chunks of 196
    int b0 = blockIdx.y * DGRP;
    int t = threadIdx.x;
    __shared__ float sk[DGRP][1024];
    for (int e = t; e < DGRP * 1024; e += 256) {
        int bb = e >> 10, k = e & 1023;
        sk[bb][k] = h2[(size_t)(b0 + bb) * 1024 + k];
    }
    __syncthreads();
    if (t >= 196) return;
    int n = nc * 196 + t;
    float acc[DGRP];
#pragma unroll
    for (int bb = 0; bb < DGRP; ++bb) acc[bb] = bias[n];
    for (int k = 0; k < 1024; ++k) {
        float wv = w[(size_t)k * 784 + n];
#pragma unroll
        for (int bb = 0; bb < DGRP; ++bb) acc[bb] += sk[bb][k] * wv;
    }
#pragma unroll
    for (int bb = 0; bb < DGRP; ++bb)
        out[1408 + (size_t)(b0 + bb) * 784 + n] = 1.f / (1.f + expf(-acc[bb]));
}

extern "C" void kernel_launch(void* const* d_in, const int* in_sizes, int n_in,
                              void* d_out, int out_size, void* d_ws, size_t ws_size,
                              hipStream_t stream) {
    const float* image = (const float*)d_in[0];
    const int*   target = (const int*)d_in[1];
    const float* w1  = (const float*)d_in[2];
    const float* b1  = (const float*)d_in[3];
    const float* w2  = (const float*)d_in[4];
    const float* b2  = (const float*)d_in[5];
    const float* Wm  = (const float*)d_in[6];
    const float* d1w = (const float*)d_in[7];
    const float* d1b = (const float*)d_in[8];
    const float* d2w = (const float*)d_in[9];
    const float* d2b = (const float*)d_in[10];
    const float* dow = (const float*)d_in[11];
    const float* dob = (const float*)d_in[12];
    float* out = (float*)d_out;
    float* ws  = (float*)d_ws;

    ushort* c1p  = (ushort*)(ws + WS_C1P);
    ushort* w2tp = (ushort*)(ws + WS_W2TP);

    int ksplit = 4;
    if (ws_size >= (size_t)(18415616 + 18 * 1179648) * 4) ksplit = 18;
    else if (ws_size >= (size_t)(18415616 + 12 * 1179648) * 4) ksplit = 12;
    else if (ws_size >= (size_t)(18415616 + 6 * 1179648) * 4) ksplit = 6;
    int nsteps = KSTEPS / ksplit / 2;
    int nwg = 144 * ksplit;

    float* s1acc = ws + WS_S12A;
    float* s2acc = ws + WS_S12A + 20480;

    convprep_kernel<<<3856, 256, 0, stream>>>(image, w1, b1, w2, c1p, w2tp);
    conv2_mfma_kernel<<<nwg, 256, 0, stream>>>(c1p, w2tp, ws + WS_CPART, nsteps, nwg);
    squash_pc_kernel<<<4608, 256, 0, stream>>>(ws + WS_CPART, b2, ws + WS_PC,
                                               ws + WS_S12A, ksplit);
    s1part_kernel<<<dim3(144, 8), 192, 0, stream>>>(Wm, ws + WS_PC, s1acc);
    c2s2_kernel<<<dim3(144, 8), 192, 0, stream>>>(Wm, ws + WS_PC, s1acc, s2acc);
    fc1_kernel<<<dim3(2, BSZ / DGRP), 256, 0, stream>>>(s2acc, target, d1w, d1b,
                                                        out, ws + WS_H1);
    fc2_kernel<<<dim3(4, BSZ / DGRP), 256, 0, stream>>>(ws + WS_H1, d2w, d2b, ws + WS_H2);
    fc3_kernel<<<dim3(4, BSZ / DGRP), 256, 0, stream>>>(ws + WS_H2, dow, dob, out);
}

// Round 17
// 405.843 us; speedup vs baseline: 1.0308x; 1.0308x over previous
//
#include <hip/hip_runtime.h>
#include <hip/hip_bf16.h>

#define EPSQ 1e-7f

#define BSZ 128
#define M2 4608           // B*36 conv2 output positions
#define K2 20736          // 81*256
#define KSTEP64 324       // 64-wide K-steps total (permuted order: icc major, khkw minor)

// ws offsets in floats (liveness-overlapped).
#define WS_C1P   0              // [0, 13,107,200) fl
#define WS_W2TP  13107200       // [13,107,200, 18,415,616) fl
#define WS_CPART 18415616
#define WS_PC    0              // 1,179,648 fl (c1p dead after conv2)
#define WS_S12A  1179648        // 40,960 fl: s1acc [0,20480) + s2acc [20480,40960)
#define WS_H1    13107200       // 65,536 (w2tp dead)
#define WS_H2    13172736       // 131,072

typedef __attribute__((ext_vector_type(8))) short short8;
typedef __attribute__((ext_vector_type(4))) float floatx4;

#define DOT8(W0, W1, P) ((W0).x*(P)[0] + (W0).y*(P)[1] + (W0).z*(P)[2] + (W0).w*(P)[3] + \
                         (W1).x*(P)[4] + (W1).y*(P)[5] + (W1).z*(P)[6] + (W1).w*(P)[7])

__device__ inline ushort bf16_rne(float x) {
    union { float f; unsigned u; } v; v.f = x;
    unsigned r = v.u + 0x7FFFu + ((v.u >> 16) & 1u);
    return (ushort)(r >> 16);
}
__device__ inline float bf16_to_f(ushort h) {
    union { unsigned u; float f; } v; v.u = ((unsigned)h) << 16;
    return v.f;
}

// ---------------- fused conv1 (blocks [0,2560)) + w2 transpose ([2560,3856)) ----
// c1p: packed hi/lo (8 ic -> 16B hi, 16B lo). w2tp: PERMUTED K order
// knew = (icc*81 + khkw)*64 + icin, packed hi/lo, so conv2's k-steps walk
// (kh,kw) at fixed ic-chunk -> overlapping input windows hit L2 back-to-back.
__global__ __launch_bounds__(256) void convprep_kernel(const float* __restrict__ img,
        const float* __restrict__ w1, const float* __restrict__ b1,
        const float* __restrict__ w2,
        ushort* __restrict__ c1p, ushort* __restrict__ w2tp) {
    __shared__ float sm[4160];
    int t = threadIdx.x;
    int bid = blockIdx.x;
    if (bid < 2560) {
        int b = bid / 20, oh = bid % 20;
        if (t < 252) sm[t] = img[b * 784 + oh * 28 + t];
        __syncthreads();
        float acc[20];
#pragma unroll
        for (int ow = 0; ow < 20; ++ow) acc[ow] = 0.f;
        for (int kh = 0; kh < 9; ++kh) {
            float row[28];
#pragma unroll
            for (int c = 0; c < 28; ++c) row[c] = sm[kh * 28 + c];
#pragma unroll
            for (int kw = 0; kw < 9; ++kw) {
                float wv = w1[(kh * 9 + kw) * 256 + t];
#pragma unroll
                for (int ow = 0; ow < 20; ++ow) acc[ow] += row[kw + ow] * wv;
            }
        }
        float bias = b1[t];
        size_t pbase = ((size_t)(b * 20 + oh) * 20) * 512 + (t >> 3) * 16 + (t & 7);
#pragma unroll
        for (int ow = 0; ow < 20; ++ow) {
            float x = fmaxf(acc[ow] + bias, 0.f);
            ushort h = bf16_rne(x);
            size_t a = pbase + (size_t)ow * 512;
            c1p[a] = h;
            c1p[a + 8] = bf16_rne(x - bf16_to_f(h));
        }
    } else {
        int pb = bid - 2560;                 // 1296 = 324 kt x 4 nt
        int kt = pb >> 2, nt = pb & 3;
        int tn = t & 63, t4 = t >> 6;
#pragma unroll
        for (int i = 0; i < 16; ++i) {
            int k = i * 4 + t4;
            sm[k * 65 + tn] = w2[(size_t)(kt * 64 + k) * 256 + nt * 64 + tn];
        }
        __syncthreads();
        int tk = t & 63;
#pragma unroll
        for (int i = 0; i < 16; ++i) {
            int n = i * 4 + t4;
            float x = sm[tk * 65 + n];
            ushort h = bf16_rne(x);
            ushort lo = bf16_rne(x - bf16_to_f(h));
            int kg = kt * 64 + tk;                 // original K: khkw*256 + ic
            int khkw = kg >> 8, ic = kg & 255;
            int knew = (((ic >> 6) * 81 + khkw) << 6) + (ic & 63);
            size_t o = (size_t)(nt * 64 + n) * 41472 + (size_t)(knew >> 3) * 16 + (knew & 7);
            w2tp[o] = h; w2tp[o + 8] = lo;
        }
    }
}

// -------- conv2 MFMA GEMM: permuted-K (icc major, khkw minor) for L2 A-reuse ----
#define LDS_AH 0
#define LDS_AL 4096
#define LDS_BH 8192
#define LDS_BL 16384
__global__ __launch_bounds__(256) void conv2_mfma_kernel(
        const ushort* __restrict__ c1p, const ushort* __restrict__ w2tp,
        float* __restrict__ part, int nsteps, int nwg) {
    int bid = blockIdx.x;
    int v = (bid & 7) * (nwg >> 3) + (bid >> 3);   // bijective: 8 | nwg
    int mt = v % 72, grp = v / 72;
    int nt = grp & 1, ks = grp >> 1;
    int t = threadIdx.x;
    int m0 = mt * 64, n0 = nt * 128;
    __shared__ __attribute__((aligned(16))) ushort lds[24576];   // 48 KB

    int sr = t >> 3, sc = t & 7;
    int mA0 = m0 + sr, mA1 = m0 + sr + 32;
    int b0_ = mA0 / 36, r0_ = mA0 % 36;
    int b1_ = mA1 / 36, r1_ = mA1 % 36;
    int pp0 = (b0_ * 20 + (r0_ / 6) * 2) * 20 + (r0_ % 6) * 2;   // position index
    int pp1 = (b1_ * 20 + (r1_ / 6) * 2) * 20 + (r1_ % 6) * 2;
    size_t wbB = (size_t)(n0 + sr) * 41472 + sc * 16;
    int wOff = sr * 64 + ((sc ^ (sr & 7)) * 8);

    int lane = t & 63, wave = t >> 6;
    int l15 = lane & 15, g = lane >> 4;
    int wrb = (wave >> 1) * 32, wcb = (wave & 1) * 64;

    floatx4 acc[2][4];
#pragma unroll
    for (int mi = 0; mi < 2; ++mi)
#pragma unroll
        for (int nj = 0; nj < 4; ++nj) acc[mi][nj] = (floatx4)0.f;

    int st0 = ks * nsteps;
    uint4 A0h, A1h, A0l, A1l, B0h, B1h, B2h, B3h, B0l, B1l, B2l, B3l;
#define LOADG64(ST) { \
        int gst = (ST); \
        int icc = gst / 81, khkw = gst - icc * 81; \
        int kh = khkw / 9, kw = khkw - kh * 9; \
        int ic2 = icc * 128 + sc * 16;                /* packed ushort offset */ \
        size_t a0 = (size_t)(pp0 + kh * 20 + kw) * 512 + ic2; \
        size_t a1 = (size_t)(pp1 + kh * 20 + kw) * 512 + ic2; \
        A0h = *(const uint4*)(c1p + a0); \
        A0l = *(const uint4*)(c1p + a0 + 8); \
        A1h = *(const uint4*)(c1p + a1); \
        A1l = *(const uint4*)(c1p + a1 + 8); \
        size_t bo = wbB + (size_t)gst * 128; \
        B0h = *(const uint4*)(w2tp + bo); \
        B0l = *(const uint4*)(w2tp + bo + 8); \
        B1h = *(const uint4*)(w2tp + bo + (size_t)32 * 41472); \
        B1l = *(const uint4*)(w2tp + bo + (size_t)32 * 41472 + 8); \
        B2h = *(const uint4*)(w2tp + bo + (size_t)64 * 41472); \
        B2l = *(const uint4*)(w2tp + bo + (size_t)64 * 41472 + 8); \
        B3h = *(const uint4*)(w2tp + bo + (size_t)96 * 41472); \
        B3l = *(const uint4*)(w2tp + bo + (size_t)96 * 41472 + 8); }

    LOADG64(st0);
    for (int st = 0; st < nsteps; ++st) {
        __syncthreads();
        *(uint4*)&lds[LDS_AH + wOff]        = A0h;
        *(uint4*)&lds[LDS_AH + wOff + 2048] = A1h;
        *(uint4*)&lds[LDS_AL + wOff]        = A0l;
        *(uint4*)&lds[LDS_AL + wOff + 2048] = A1l;
        *(uint4*)&lds[LDS_BH + wOff]        = B0h;
        *(uint4*)&lds[LDS_BH + wOff + 2048] = B1h;
        *(uint4*)&lds[LDS_BH + wOff + 4096] = B2h;
        *(uint4*)&lds[LDS_BH + wOff + 6144] = B3h;
        *(uint4*)&lds[LDS_BL + wOff]        = B0l;
        *(uint4*)&lds[LDS_BL + wOff + 2048] = B1l;
        *(uint4*)&lds[LDS_BL + wOff + 4096] = B2l;
        *(uint4*)&lds[LDS_BL + wOff + 6144] = B3l;
        __syncthreads();
        if (st + 1 < nsteps) LOADG64(st0 + st + 1);

#pragma unroll
        for (int kk = 0; kk < 2; ++kk) {
            int sl = kk * 4 + g;
            short8 ah[2], al[2], bh[4], bl[4];
#pragma unroll
            for (int mi = 0; mi < 2; ++mi) {
                int r = wrb + mi * 16 + l15;
                int ro = r * 64 + ((sl ^ (r & 7)) * 8);
                ah[mi] = *(const short8*)&lds[LDS_AH + ro];
                al[mi] = *(const short8*)&lds[LDS_AL + ro];
            }
#pragma unroll
            for (int nj = 0; nj < 4; ++nj) {
                int c = wcb + nj * 16 + l15;
                int co = c * 64 + ((sl ^ (c & 7)) * 8);
                bh[nj] = *(const short8*)&lds[LDS_BH + co];
                bl[nj] = *(const short8*)&lds[LDS_BL + co];
            }
#pragma unroll
            for (int mi = 0; mi < 2; ++mi)
#pragma unroll
                for (int nj = 0; nj < 4; ++nj) {
                    acc[mi][nj] = __builtin_amdgcn_mfma_f32_16x16x32_bf16(ah[mi], bh[nj], acc[mi][nj], 0, 0, 0);
                    acc[mi][nj] = __builtin_amdgcn_mfma_f32_16x16x32_bf16(ah[mi], bl[nj], acc[mi][nj], 0, 0, 0);
                    acc[mi][nj] = __builtin_amdgcn_mfma_f32_16x16x32_bf16(al[mi], bh[nj], acc[mi][nj], 0, 0, 0);
                }
        }
    }
    __syncthreads();
    float* ldsf = (float*)lds;
#pragma unroll
    for (int mi = 0; mi < 2; ++mi)
#pragma unroll
        for (int nj = 0; nj < 4; ++nj) {
            int col = wcb + nj * 16 + l15;
            int rw = wrb + mi * 16 + (lane >> 4) * 4;
#pragma unroll
            for (int r = 0; r < 4; ++r)
                ldsf[(rw + r) * 132 + col] = acc[mi][nj][r];
        }
    __syncthreads();
    size_t obase = (size_t)ks * M2 * 256;
#pragma unroll
    for (int i = 0; i < 8; ++i) {
        int f = i * 256 + t;          // float4 id 0..2047
        int row = f >> 5, c4 = f & 31;
        float4 val = *(const float4*)&ldsf[row * 132 + c4 * 4];
        *(float4*)&part[obase + (size_t)(m0 + row) * 256 + n0 + c4 * 4] = val;
    }
}

// -------- reduce k-split partials + bias + relu + squash(8) -> pc; zero s12acc --
__global__ __launch_bounds__(256) void squash_pc_kernel(const float* __restrict__ part,
        const float* __restrict__ b2, float* __restrict__ pc,
        float* __restrict__ s12acc, int nsplit) {
    int m = blockIdx.x;
    int n = threadIdx.x;
    if (m < 160) s12acc[m * 256 + n] = 0.f;   // zero s1acc+s2acc (40960 fl)
    size_t idx = (size_t)m * 256 + n;
    const size_t stride = (size_t)M2 * 256;
    float v = 0.f;
    for (int s = 0; s < nsplit; ++s) v += part[idx + s * stride];
    v = fmaxf(v + b2[n], 0.f);
    float sq = v * v;
    sq += __shfl_xor(sq, 1, 8);
    sq += __shfl_xor(sq, 2, 8);
    sq += __shfl_xor(sq, 4, 8);
    float scale = sq / ((1.f + sq) * sqrtf(sq + EPSQ));
    pc[idx] = v * scale;
}

// -------- s1: grid (144 x 8), W in regs, atomic accumulation into s1acc ---------
__global__ __launch_bounds__(192) void s1part_kernel(const float* __restrict__ Wm,
        const float* __restrict__ pc, float* __restrict__ s1acc) {
    int ic = blockIdx.x, bg = blockIdx.y;
    int i0 = ic * 8, b0 = bg * 16;
    int t = threadIdx.x;
    __shared__ float pcl[16][68];
    for (int e = t; e < 1024; e += 192) {
        int bl = e >> 6, off = e & 63;
        pcl[bl][off] = pc[(size_t)(b0 + bl) * 9216 + i0 * 8 + off];
    }
    __syncthreads();
    if (t >= 160) return;
    float4 w[8][2];
#pragma unroll
    for (int ii = 0; ii < 8; ++ii) {
        const float4* wp = (const float4*)&Wm[(size_t)(i0 + ii) * 1280 + t * 8];
        w[ii][0] = wp[0]; w[ii][1] = wp[1];
    }
    for (int bl = 0; bl < 16; ++bl) {
        float s = 0.f;
#pragma unroll
        for (int ii = 0; ii < 8; ++ii) {
            const float* p = &pcl[bl][ii * 8];
            s += DOT8(w[ii][0], w[ii][1], p);
        }
        atomicAdd(&s1acc[(b0 + bl) * 160 + t], s);
    }
}

// -------- c2s2: v1 squash folded in; agreement+softmax; atomic s2 accumulation --
__global__ __launch_bounds__(192) void c2s2_kernel(const float* __restrict__ Wm,
        const float* __restrict__ pc, const float* __restrict__ s1acc,
        float* __restrict__ s2acc) {
    int ic = blockIdx.x, bg = blockIdx.y;
    int i0 = ic * 8, b0 = bg * 16;
    int t = threadIdx.x;
    __shared__ float pcl[16][68];
    __shared__ float uvl[8][16][10];
    for (int e = t; e < 1024; e += 192) {
        int bl = e >> 6, off = e & 63;
        pcl[bl][off] = pc[(size_t)(b0 + bl) * 9216 + i0 * 8 + off];
    }
    __syncthreads();
    int j = t >> 4;
    float4 w[8][2];
    if (t < 160) {
#pragma unroll
        for (int ii = 0; ii < 8; ++ii) {
            const float4* wp = (const float4*)&Wm[(size_t)(i0 + ii) * 1280 + t * 8];
            w[ii][0] = wp[0]; w[ii][1] = wp[1];
        }
        for (int bl = 0; bl < 16; ++bl) {
            float s1v = s1acc[(b0 + bl) * 160 + t] * 0.1f;
            float q = s1v * s1v;
            q += __shfl_xor(q, 1, 16);
            q += __shfl_xor(q, 2, 16);
            q += __shfl_xor(q, 4, 16);
            q += __shfl_xor(q, 8, 16);
            float vv = s1v * q / ((1.f + q) * sqrtf(q + EPSQ));
#pragma unroll
            for (int ii = 0; ii < 8; ++ii) {
                const float* p = &pcl[bl][ii * 8];
                float u = DOT8(w[ii][0], w[ii][1], p);
                float pr = u * vv;
                pr += __shfl_xor(pr, 1, 16);
                pr += __shfl_xor(pr, 2, 16);
                pr += __shfl_xor(pr, 4, 16);
                pr += __shfl_xor(pr, 8, 16);
                if ((t & 15) == 0) uvl[ii][bl][j] = pr;
            }
        }
    }
    __syncthreads();
    if (t < 128) {
        int ii = t >> 4, bl = t & 15;
        float* uv = uvl[ii][bl];
        float mx = uv[0];
#pragma unroll
        for (int jj = 1; jj < 10; ++jj) mx = fmaxf(mx, uv[jj]);
        float sum = 0.f;
        float ex[10];
#pragma unroll
        for (int jj = 0; jj < 10; ++jj) { ex[jj] = expf(uv[jj] - mx); sum += ex[jj]; }
        float inv = 1.f / sum;
#pragma unroll
        for (int jj = 0; jj < 10; ++jj) uv[jj] = ex[jj] * inv;
    }
    __syncthreads();
    if (t >= 160) return;
    for (int bl = 0; bl < 16; ++bl) {
        float acc = 0.f;
#pragma unroll
        for (int ii = 0; ii < 8; ++ii) {
            const float* p = &pcl[bl][ii * 8];
            float u = DOT8(w[ii][0], w[ii][1], p);
            acc += uvl[ii][bl][j] * u;
        }
        atomicAdd(&s2acc[(b0 + bl) * 160 + t], acc);
    }
}

// ======== batch-grouped decoder: weights read 32x instead of 128x ===============
#define DGRP 4

// -------- fc1: fused v2-squash/norm/argmax/mask preamble + GEMM -----------------
__global__ __launch_bounds__(256) void fc1_kernel(const float* __restrict__ s2acc,
        const int* __restrict__ target, const float* __restrict__ w,
        const float* __restrict__ bias, float* __restrict__ out,
        float* __restrict__ h1) {
    int nc = blockIdx.x;                 // 0..1
    int b0 = blockIdx.y * DGRP;
    int t = threadIdx.x;
    __shared__ float sk[DGRP][160];
    __shared__ float nl[DGRP][10];
    for (int bb = 0; bb < DGRP; ++bb) {
        if (t < 160) {
            int b = b0 + bb;
            float s = s2acc[b * 160 + t];
            float sq = s * s;
            sq += __shfl_xor(sq, 1, 16);
            sq += __shfl_xor(sq, 2, 16);
            sq += __shfl_xor(sq, 4, 16);
            sq += __shfl_xor(sq, 8, 16);
            float v = s * sq / ((1.f + sq) * sqrtf(sq + EPSQ));
            float vsq = v * v;
            vsq += __shfl_xor(vsq, 1, 16);
            vsq += __shfl_xor(vsq, 2, 16);
            vsq += __shfl_xor(vsq, 4, 16);
            vsq += __shfl_xor(vsq, 8, 16);
            float norm = sqrtf(vsq + EPSQ);
            int j = t >> 4;
            sk[bb][t] = (j == target[b]) ? v : 0.f;
            if ((t & 15) == 0) {
                nl[bb][j] = norm;
                if (nc == 0) out[b * 10 + j] = norm;
            }
        }
    }
    __syncthreads();
    if (nc == 0 && t < DGRP) {
        float best = nl[t][0]; int am = 0;
#pragma unroll
        for (int jj = 1; jj < 10; ++jj) if (nl[t][jj] > best) { best = nl[t][jj]; am = jj; }
        out[1280 + b0 + t] = (float)am;
    }
    int n = nc * 256 + t;
    float acc[DGRP];
#pragma unroll
    for (int bb = 0; bb < DGRP; ++bb) acc[bb] = bias[n];
    for (int k = 0; k < 160; ++k) {
        float wv = w[k * 512 + n];
#pragma unroll
        for (int bb = 0; bb < DGRP; ++bb) acc[bb] += sk[bb][k] * wv;
    }
#pragma unroll
    for (int bb = 0; bb < DGRP; ++bb)
        h1[(size_t)(b0 + bb) * 512 + n] = fmaxf(acc[bb], 0.f);
}

// -------- fc2: relu, batch-grouped ----------------------------------------------
__global__ __launch_bounds__(256) void fc2_kernel(const float* __restrict__ h1,
        const float* __restrict__ w, const float* __restrict__ bias,
        float* __restrict__ h2) {
    int nc = blockIdx.x;                 // 0..3
    int b0 = blockIdx.y * DGRP;
    int t = threadIdx.x;
    __shared__ float sk[DGRP][512];
    for (int e = t; e < DGRP * 512; e += 256) {
        int bb = e >> 9, k = e & 511;
        sk[bb][k] = h1[(size_t)(b0 + bb) * 512 + k];
    }
    __syncthreads();
    int n = nc * 256 + t;
    float acc[DGRP];
#pragma unroll
    for (int bb = 0; bb < DGRP; ++bb) acc[bb] = bias[n];
    for (int k = 0; k < 512; ++k) {
        float wv = w[(size_t)k * 1024 + n];
#pragma unroll
        for (int bb = 0; bb < DGRP; ++bb) acc[bb] += sk[bb][k] * wv;
    }
#pragma unroll
    for (int bb = 0; bb < DGRP; ++bb)
        h2[(size_t)(b0 + bb) * 1024 + n] = fmaxf(acc[bb], 0.f);
}

// -------- fc3: sigmoid, batch-grouped -------------------------------------------
__global__ __launch_bounds__(256) void fc3_kernel(const float* __restrict__ h2,
        const float* __restrict__ w, const float* __restrict__ bias,
        float* __restrict__ out) {
    int nc = blockIdx.x;                 // 0..3, chunks of 196
    int b0 = blockIdx.y * DGRP;
    int t = threadIdx.x;
    __shared__ float sk[DGRP][1024];
    for (int e = t; e < DGRP * 1024; e += 256) {
        int bb = e >> 10, k = e & 1023;
        sk[bb][k] = h2[(size_t)(b0 + bb) * 1024 + k];
    }
    __syncthreads();
    if (t >= 196) return;
    int n = nc * 196 + t;
    float acc[DGRP];
#pragma unroll
    for (int bb = 0; bb < DGRP; ++bb) acc[bb] = bias[n];
    for (int k = 0; k < 1024; ++k) {
        float wv = w[(size_t)k * 784 + n];
#pragma unroll
        for (int bb = 0; bb < DGRP; ++bb) acc[bb] += sk[bb][k] * wv;
    }
#pragma unroll
    for (int bb = 0; bb < DGRP; ++bb)
        out[1408 + (size_t)(b0 + bb) * 784 + n] = 1.f / (1.f + expf(-acc[bb]));
}

extern "C" void kernel_launch(void* const* d_in, const int* in_sizes, int n_in,
                              void* d_out, int out_size, void* d_ws, size_t ws_size,
                              hipStream_t stream) {
    const float* image = (const float*)d_in[0];
    const int*   target = (const int*)d_in[1];
    const float* w1  = (const float*)d_in[2];
    const float* b1  = (const float*)d_in[3];
    const float* w2  = (const float*)d_in[4];
    const float* b2  = (const float*)d_in[5];
    const float* Wm  = (const float*)d_in[6];
    const float* d1w = (const float*)d_in[7];
    const float* d1b = (const float*)d_in[8];
    const float* d2w = (const float*)d_in[9];
    const float* d2b = (const float*)d_in[10];
    const float* dow = (const float*)d_in[11];
    const float* dob = (const float*)d_in[12];
    float* out = (float*)d_out;
    float* ws  = (float*)d_ws;

    ushort* c1p  = (ushort*)(ws + WS_C1P);
    ushort* w2tp = (ushort*)(ws + WS_W2TP);

    // ksplit must divide 324 (64-wide permuted K-steps): tiers 12 / 6 / 4
    int ksplit = 4;
    if (ws_size >= (size_t)(18415616 + 12 * 1179648) * 4) ksplit = 12;
    else if (ws_size >= (size_t)(18415616 + 6 * 1179648) * 4) ksplit = 6;
    int nsteps = KSTEP64 / ksplit;
    int nwg = 144 * ksplit;

    float* s1acc = ws + WS_S12A;
    float* s2acc = ws + WS_S12A + 20480;

    convprep_kernel<<<3856, 256, 0, stream>>>(image, w1, b1, w2, c1p, w2tp);
    conv2_mfma_kernel<<<nwg, 256, 0, stream>>>(c1p, w2tp, ws + WS_CPART, nsteps, nwg);
    squash_pc_kernel<<<4608, 256, 0, stream>>>(ws + WS_CPART, b2, ws + WS_PC,
                                               ws + WS_S12A, ksplit);
    s1part_kernel<<<dim3(144, 8), 192, 0, stream>>>(Wm, ws + WS_PC, s1acc);
    c2s2_kernel<<<dim3(144, 8), 192, 0, stream>>>(Wm, ws + WS_PC, s1acc, s2acc);
    fc1_kernel<<<dim3(2, BSZ / DGRP), 256, 0, stream>>>(s2acc, target, d1w, d1b,
                                                        out, ws + WS_H1);
    fc2_kernel<<<dim3(4, BSZ / DGRP), 256, 0, stream>>>(ws + WS_H1, d2w, d2b, ws + WS_H2);
    fc3_kernel<<<dim3(4, BSZ / DGRP), 256, 0, stream>>>(ws + WS_H2, dow, dob, out);
}